// Round 4
// baseline (263.266 us; speedup 1.0000x reference)
//
#include <hip/hip_runtime.h>
#include <cstddef>
#include <cstdint>

#define F 128
#define C_OUT 10
#define SB 256   // scan block size

typedef short bf16x8 __attribute__((ext_vector_type(8)));
typedef float f32x4  __attribute__((ext_vector_type(4)));
typedef float f32x2  __attribute__((ext_vector_type(2)));

__device__ __forceinline__ unsigned short bf16_rne(float f) {
  unsigned u = __float_as_uint(f);
  return (unsigned short)((u + 0x7FFFu + ((u >> 16) & 1u)) >> 16);
}

// ---------------- GRU weight evolution (both layers, single-bf16 RNE) + zero counts ----
__global__ void gru_evolve2_k(const float* __restrict__ W01, const float* __restrict__ wih1,
                              const float* __restrict__ whh1, const float* __restrict__ bih1,
                              const float* __restrict__ bhh1,
                              const float* __restrict__ W02, const float* __restrict__ wih2,
                              const float* __restrict__ whh2, const float* __restrict__ bih2,
                              const float* __restrict__ bhh2,
                              unsigned short* __restrict__ Bhi1, unsigned short* __restrict__ Bhi2,
                              int* __restrict__ counts, int n) {
  if ((int)blockIdx.x >= 128) {
    int i = ((int)blockIdx.x - 128) * SB + threadIdx.x;
    if (i < n) counts[i] = 0;
    return;
  }
  int t = blockIdx.x * 256 + threadIdx.x;     // 0..32767
  int layer = t >> 14;
  int tt = t & 16383;
  const float* W0  = layer ? W02  : W01;
  const float* wih = layer ? wih2 : wih1;
  const float* whh = layer ? whh2 : whh1;
  const float* bih = layer ? bih2 : bih1;
  const float* bhh = layer ? bhh2 : bhh1;
  unsigned short* Bhi = layer ? Bhi2 : Bhi1;
  int i = tt >> 7, j = tt & 127;      // i = k (feature) index, j = w_col index
  const float4* w0r = (const float4*)(W0 + (size_t)i * F);
  float gi[3], gh[3];
#pragma unroll
  for (int g = 0; g < 3; ++g) {
    const float4* wr = (const float4*)(wih + (size_t)(g * F + j) * F);
    const float4* hr = (const float4*)(whh + (size_t)(g * F + j) * F);
    float si = 0.f, sh = 0.f;
    for (int k = 0; k < F / 4; ++k) {
      float4 a = w0r[k];
      float4 b = wr[k];
      float4 c = hr[k];
      si += a.x * b.x + a.y * b.y + a.z * b.z + a.w * b.w;
      sh += a.x * c.x + a.y * c.y + a.z * c.z + a.w * c.w;
    }
    gi[g] = si + bih[g * F + j];
    gh[g] = sh + bhh[g * F + j];
  }
  float r = 1.0f / (1.0f + expf(-(gi[0] + gh[0])));
  float z = 1.0f / (1.0f + expf(-(gi[1] + gh[1])));
  float nn = tanhf(gi[2] + r * gh[2]);
  float val = (1.0f - z) * nn + z * W0[(size_t)i * F + j];

  int kstep = i >> 5, kl = i & 31;
  int lane = (kl >> 3) * 16 + (j & 15);
  int tile = j >> 4;
  int idx = ((kstep * 8 + tile) * 64 + lane) * 8 + (kl & 7);
  Bhi[idx] = bf16_rne(val);
}

// ---------------- CSR build ----------------
__global__ void count_rank_k(const int* __restrict__ dst, int* __restrict__ counts,
                             int* __restrict__ rank, int E) {
  int e = blockIdx.x * blockDim.x + threadIdx.x;
  if (e < E) rank[e] = atomicAdd(&counts[dst[e]], 1);
}

__global__ void scan_local_k(const int* __restrict__ counts, int* __restrict__ incl,
                             int* __restrict__ blocksum, int n) {
  __shared__ int sh[SB];
  int gid = blockIdx.x * SB + threadIdx.x;
  int v = (gid < n) ? counts[gid] : 0;
  sh[threadIdx.x] = v;
  __syncthreads();
  for (int off = 1; off < SB; off <<= 1) {
    int t = 0;
    if ((int)threadIdx.x >= off) t = sh[threadIdx.x - off];
    __syncthreads();
    if ((int)threadIdx.x >= off) sh[threadIdx.x] += t;
    __syncthreads();
  }
  if (gid < n) incl[gid] = sh[threadIdx.x];
  if (threadIdx.x == SB - 1) blocksum[blockIdx.x] = sh[SB - 1];
}

__global__ void scan_finish_k(const int* __restrict__ counts, const int* __restrict__ incl,
                              const int* __restrict__ blocksum, int* __restrict__ rowptr,
                              float* __restrict__ dinv, int n, int nb) {
  __shared__ int sh[SB];
  __shared__ int orig[SB];
  int v = ((int)threadIdx.x < nb) ? blocksum[threadIdx.x] : 0;
  sh[threadIdx.x] = v;
  orig[threadIdx.x] = v;
  __syncthreads();
  for (int off = 1; off < SB; off <<= 1) {
    int t = 0;
    if ((int)threadIdx.x >= off) t = sh[threadIdx.x - off];
    __syncthreads();
    if ((int)threadIdx.x >= off) sh[threadIdx.x] += t;
    __syncthreads();
  }
  int myoff = sh[blockIdx.x] - orig[blockIdx.x];
  int gid = blockIdx.x * SB + threadIdx.x;
  if (gid >= n) return;
  int c = counts[gid];
  int inc = myoff + incl[gid];
  rowptr[gid] = inc - c;
  dinv[gid] = rsqrtf((float)c + 1.0f);
  if (gid == n - 1) rowptr[n] = inc;
}

// fill stores PRE-SHIFTED src (src<<7 = byte offset of the 128B fp8 row).
__device__ __forceinline__ void fill_body(int bid, const int* __restrict__ src,
                                          const int* __restrict__ dst,
                                          const int* __restrict__ rank,
                                          const int* __restrict__ rowptr,
                                          int* __restrict__ csr_src, int E) {
  int e = bid * 256 + (int)threadIdx.x;
  if (e < E) {
    int d = dst[e];
    csr_src[rowptr[d] + rank[e]] = src[e] << 7;
  }
}

// ---------------- MFMA GEMM: fp8 rows (128 B), single-bf16 inputs --------------------
// Transposed MFMA: D = W' (A) x X^T (B); lane owns x_row = lane&15, 4 consecutive
// w_cols per tile. Single-bf16 RNE inputs (verified: absmax unchanged vs split).
// Epilogue: fp8 e4m3 encode (HW cvt_pk_fp8_f32); row = 32 dwords = one cache line.
__device__ __forceinline__ void gemm_body(int bid, const float* __restrict__ X,
                                          const unsigned short* __restrict__ Bhi,
                                          const float* __restrict__ dinv,
                                          unsigned* __restrict__ Y, int nrows) {
  int wid = bid * 4 + ((int)threadIdx.x >> 6);
  int lane = threadIdx.x & 63;
  int ng = (nrows + 15) >> 4;
  if (wid >= ng) return;
  int g = __builtin_amdgcn_readfirstlane(wid);
  int q = lane >> 4, m = lane & 15;
  int rowA = g * 16 + m;
  if (rowA >= nrows) rowA = nrows - 1;

  f32x4 acc[8];
#pragma unroll
  for (int t = 0; t < 8; ++t) { acc[t].x = 0.f; acc[t].y = 0.f; acc[t].z = 0.f; acc[t].w = 0.f; }

#pragma unroll
  for (int s = 0; s < 4; ++s) {
    const float* xp = X + (size_t)rowA * F + s * 32 + q * 8;
    float4 xa = *(const float4*)xp;
    float4 xb = *(const float4*)(xp + 4);
    float xv[8] = {xa.x, xa.y, xa.z, xa.w, xb.x, xb.y, xb.z, xb.w};
    bf16x8 xh;
#pragma unroll
    for (int j = 0; j < 8; ++j) xh[j] = (short)bf16_rne(xv[j]);
#pragma unroll
    for (int t = 0; t < 8; ++t) {
      size_t boff = ((size_t)(s * 8 + t) * 64 + lane) * 8;
      bf16x8 wh = *(const bf16x8*)(Bhi + boff);
      acc[t] = __builtin_amdgcn_mfma_f32_16x16x32_bf16(wh, xh, acc[t], 0, 0, 0);
    }
  }

  int row = g * 16 + m;
  if (row < nrows) {
    float dd = dinv[row];
    unsigned* yr = Y + (size_t)row * 32 + q;   // lane q owns dword t*4+q
#pragma unroll
    for (int t = 0; t < 8; ++t) {
      int p = __builtin_amdgcn_cvt_pk_fp8_f32(dd * acc[t].x, dd * acc[t].y, 0, false);
      p = __builtin_amdgcn_cvt_pk_fp8_f32(dd * acc[t].z, dd * acc[t].w, p, true);
      yr[t * 4] = (unsigned)p;
    }
  }
}

__global__ void gemm_mfma_k(const float* __restrict__ X, const unsigned short* __restrict__ Bhi,
                            const float* __restrict__ dinv, unsigned* __restrict__ Y,
                            int nrows) {
  gemm_body(blockIdx.x, X, Bhi, dinv, Y, nrows);
}

// fused: blocks [0, ngemm) do layer-1 gemm; [ngemm, ...) do csr fill.
__global__ void fill_gemm_k(const float* __restrict__ X, const unsigned short* __restrict__ Bhi,
                            const float* __restrict__ dinv, unsigned* __restrict__ Y,
                            int nrows, int ngemm,
                            const int* __restrict__ src, const int* __restrict__ dst,
                            const int* __restrict__ rank, const int* __restrict__ rowptr,
                            int* __restrict__ csr_src, int E) {
  if ((int)blockIdx.x < ngemm)
    gemm_body(blockIdx.x, X, Bhi, dinv, Y, nrows);
  else
    fill_body((int)blockIdx.x - ngemm, src, dst, rank, rowptr, csr_src, E);
}

// ---------------- gather aggregation: fp8 rows (128 B), forced-wide MLP --------------
// One wave per node. Lanes 0-31 even edges, 32-63 odd edges; lane (half,hm) loads one
// dword = 4 fp8 cols (half-wave covers a full 128B row).
// R0-R3 lesson: time is invariant to instruction count / batch shape / dependent
// rounds -- but VGPR_Count was 28, i.e. the compiler (optimizing for occupancy with
// no launch bounds) re-serialized every variant to ~4 outstanding vmem ops. This
// version FORCES a wide pipeline: __launch_bounds__(256,4) caps occupancy at 16
// waves/CU (VGPR budget 128) and the 32-edge batch keeps 16 csr values + 16 gather
// results structurally live -> 32 outstanding requests per wave. ~95% of nodes
// (deg<=32) finish in ONE clamped+masked csr->gather round.
template <bool FUSE_LOGITS>
__global__ __launch_bounds__(256, 4)
void agg_fp8_k(const int* __restrict__ rowptr, const int* __restrict__ csr_src,
               const float* __restrict__ dinv, const unsigned* __restrict__ xwp,
               float* __restrict__ hout,
               const float* __restrict__ lw, const float* __restrict__ lb,
               float* __restrict__ outp, int n) {
  int wave = (int)((blockIdx.x * blockDim.x + threadIdx.x) >> 6);
  int lane = threadIdx.x & 63;
  if (wave >= n) return;
  int node = __builtin_amdgcn_readfirstlane(wave);
  int half = lane >> 5, hm = lane & 31;
  const char* __restrict__ cb = (const char*)xwp;   // row = 128 bytes
  unsigned loff = (unsigned)(hm << 2);

  // self-loop gather first: depends only on node, overlaps the rowptr loads
  unsigned uself = *(const unsigned*)(cb + ((((unsigned)node) << 7) | loff));

  int b = rowptr[node], e = rowptr[node + 1];
  float dd = dinv[node];
  if (half) uself = 0u;

  f32x2 acc0 = {0.f, 0.f}, acc1 = {0.f, 0.f};
  f32x2 bcc0 = {0.f, 0.f}, bcc1 = {0.f, 0.f};

#define DEC(U, A, B)                                           \
  do {                                                         \
    (A) += __builtin_amdgcn_cvt_pk_f32_fp8((int)(U), false);   \
    (B) += __builtin_amdgcn_cvt_pk_f32_fp8((int)(U), true);    \
  } while (0)

  DEC(uself, acc0, acc1);

  const int* __restrict__ cp = csr_src + half;   // cp[i+2k] = edge i+2k+half
  int i = b;
  // full 32-edge batches: 16 csr loads then 16 gathers, ALL kept in flight
  for (; i + 32 <= e; i += 32) {
    int sv[16];
#pragma unroll
    for (int k = 0; k < 16; ++k) sv[k] = cp[i + 2 * k];
    unsigned uv[16];
#pragma unroll
    for (int k = 0; k < 16; ++k)
      uv[k] = *(const unsigned*)(cb + (((unsigned)sv[k]) | loff));
#pragma unroll
    for (int k = 0; k < 16; ++k) {
      if (k & 1) DEC(uv[k], bcc0, bcc1); else DEC(uv[k], acc0, acc1);
    }
  }
  // tail: ONE clamped + masked 32-edge batch (covers any remainder 1..31)
  if (i < e) {
    int em1 = e - 1;
    int ih = i + half;
    int sv[16];
#pragma unroll
    for (int k = 0; k < 16; ++k) {
      int off = ih + 2 * k;
      sv[k] = csr_src[off > em1 ? em1 : off];
    }
    unsigned uv[16];
#pragma unroll
    for (int k = 0; k < 16; ++k)
      uv[k] = *(const unsigned*)(cb + (((unsigned)sv[k]) | loff));
#pragma unroll
    for (int k = 0; k < 16; ++k) {
      unsigned u = (ih + 2 * k < e) ? uv[k] : 0u;
      if (k & 1) DEC(u, bcc0, bcc1); else DEC(u, acc0, acc1);
    }
  }
#undef DEC
  acc0 += bcc0;
  acc1 += bcc1;

  // combine the two halves (both end up with the full sum)
  acc0.x += __shfl_xor(acc0.x, 32);
  acc0.y += __shfl_xor(acc0.y, 32);
  acc1.x += __shfl_xor(acc1.x, 32);
  acc1.y += __shfl_xor(acc1.y, 32);

  float h0 = fmaxf(dd * acc0.x, 0.f);
  float h1 = fmaxf(dd * acc0.y, 0.f);
  float h2 = fmaxf(dd * acc1.x, 0.f);
  float h3 = fmaxf(dd * acc1.y, 0.f);

  if (!FUSE_LOGITS) {
    if (half == 0) {
      *(float4*)(hout + (size_t)node * F + hm * 4) = make_float4(h0, h1, h2, h3);
    }
  } else {
    float acc[C_OUT];
#pragma unroll
    for (int c = 0; c < C_OUT; ++c) {
      float4 w = *(const float4*)(lw + (size_t)c * F + hm * 4);
      float v = h0 * w.x + h1 * w.y + h2 * w.z + h3 * w.w;
      v += __shfl_xor(v, 1); v += __shfl_xor(v, 2);
      v += __shfl_xor(v, 4); v += __shfl_xor(v, 8);
      v += __shfl_xor(v, 16);
      acc[c] = v + lb[c];
    }
    float mx = acc[0];
#pragma unroll
    for (int c = 1; c < C_OUT; ++c) mx = fmaxf(mx, acc[c]);
    float s = 0.f;
#pragma unroll
    for (int c = 0; c < C_OUT; ++c) s += expf(acc[c] - mx);
    float lse = mx + logf(s);
#pragma unroll
    for (int c = 0; c < C_OUT; ++c)
      if (lane == c) outp[(size_t)node * C_OUT + c] = acc[c] - lse;
  }
}

extern "C" void kernel_launch(void* const* d_in, const int* in_sizes, int n_in,
                              void* d_out, int out_size, void* d_ws, size_t ws_size,
                              hipStream_t stream) {
  const float* x    = (const float*)d_in[0];
  const int*   ei   = (const int*)d_in[1];
  const float* W1   = (const float*)d_in[2];
  const float* wih1 = (const float*)d_in[3];
  const float* whh1 = (const float*)d_in[4];
  const float* bih1 = (const float*)d_in[5];
  const float* bhh1 = (const float*)d_in[6];
  const float* W2   = (const float*)d_in[7];
  const float* wih2 = (const float*)d_in[8];
  const float* whh2 = (const float*)d_in[9];
  const float* bih2 = (const float*)d_in[10];
  const float* bhh2 = (const float*)d_in[11];
  const float* lw   = (const float*)d_in[12];
  const float* lb   = (const float*)d_in[13];
  float* out = (float*)d_out;

  int N = in_sizes[0] / F;
  int E = in_sizes[1] / 2;
  const int* src = ei;
  const int* dst = ei + E;
  int nb = (N + SB - 1) / SB;   // 196 (must be <= 256)
  int ng = (N + 15) / 16;
  int ngemm = (ng + 3) / 4;
  int nfill = (E + 255) / 256;
  int nagg = (N + 3) / 4;

  float* ws = (float*)d_ws;
  unsigned* bufA = (unsigned*)ws;                // N*32 dwords (fp8 rows, 128 B)
  float* bufB = (float*)(bufA + (size_t)N * 32); // N*F floats (h)
  float* dinv = bufB + (size_t)N * F;            // N
  unsigned short* Bhi1 = (unsigned short*)(dinv + N);  // 16384
  unsigned short* Bhi2 = Bhi1 + F * F;                 // 16384
  int* counts = (int*)(Bhi2 + F * F);            // N
  int* rowptr = counts + N;                      // N+1
  int* rank   = rowptr + N + 1;                  // E
  int* incl   = rank + E;                        // N
  int* blocksum = incl + N;                      // 256
  int* csr_src = blocksum + 256;                 // E

  gru_evolve2_k<<<128 + nb, 256, 0, stream>>>(W1, wih1, whh1, bih1, bhh1,
                                              W2, wih2, whh2, bih2, bhh2,
                                              Bhi1, Bhi2, counts, N);

  count_rank_k<<<(E + 255) / 256, 256, 0, stream>>>(dst, counts, rank, E);
  scan_local_k<<<nb, SB, 0, stream>>>(counts, incl, blocksum, N);
  scan_finish_k<<<nb, SB, 0, stream>>>(counts, incl, blocksum, rowptr, dinv, N, nb);

  // layer 1 gemm + csr fill (independent; fused dispatch)
  fill_gemm_k<<<ngemm + nfill, 256, 0, stream>>>(x, Bhi1, dinv, bufA, N, ngemm,
                                                 src, dst, rank, rowptr, csr_src, E);
  agg_fp8_k<false><<<nagg, 256, 0, stream>>>(rowptr, csr_src, dinv, bufA, bufB,
                                             nullptr, nullptr, nullptr, N);

  // layer 2 (logits fused)
  gemm_mfma_k<<<ngemm, 256, 0, stream>>>(bufB, Bhi2, dinv, bufA, N);
  agg_fp8_k<true><<<nagg, 256, 0, stream>>>(rowptr, csr_src, dinv, bufA, nullptr,
                                            lw, lb, out, N);
}

// Round 5
// 261.042 us; speedup vs baseline: 1.0085x; 1.0085x over previous
//
#include <hip/hip_runtime.h>
#include <cstddef>
#include <cstdint>

#define F 128
#define C_OUT 10
#define SB 256   // scan block size

typedef short bf16x8 __attribute__((ext_vector_type(8)));
typedef float f32x4  __attribute__((ext_vector_type(4)));
typedef float f32x2  __attribute__((ext_vector_type(2)));

__device__ __forceinline__ unsigned short bf16_rne(float f) {
  unsigned u = __float_as_uint(f);
  return (unsigned short)((u + 0x7FFFu + ((u >> 16) & 1u)) >> 16);
}

// Forced-MLP gather: 8 global_load_dword issued back-to-back inside ONE asm block
// with a single vmcnt(0). The compiler cannot re-serialize this into 4-deep groups
// (which rocprof shows it did for every C-level variant: VGPR_Count 28-32 in R0-R4).
__device__ __forceinline__ void gather8(
    const char* p0, const char* p1, const char* p2, const char* p3,
    const char* p4, const char* p5, const char* p6, const char* p7,
    unsigned& u0, unsigned& u1, unsigned& u2, unsigned& u3,
    unsigned& u4, unsigned& u5, unsigned& u6, unsigned& u7) {
  asm volatile(
      "global_load_dword %0, %[q0], off\n\t"
      "global_load_dword %1, %[q1], off\n\t"
      "global_load_dword %2, %[q2], off\n\t"
      "global_load_dword %3, %[q3], off\n\t"
      "global_load_dword %4, %[q4], off\n\t"
      "global_load_dword %5, %[q5], off\n\t"
      "global_load_dword %6, %[q6], off\n\t"
      "global_load_dword %7, %[q7], off\n\t"
      "s_waitcnt vmcnt(0)"
      : "=&v"(u0), "=&v"(u1), "=&v"(u2), "=&v"(u3),
        "=&v"(u4), "=&v"(u5), "=&v"(u6), "=&v"(u7)
      : [q0] "v"(p0), [q1] "v"(p1), [q2] "v"(p2), [q3] "v"(p3),
        [q4] "v"(p4), [q5] "v"(p5), [q6] "v"(p6), [q7] "v"(p7));
}

__device__ __forceinline__ void gather4(
    const char* p0, const char* p1, const char* p2, const char* p3,
    unsigned& u0, unsigned& u1, unsigned& u2, unsigned& u3) {
  asm volatile(
      "global_load_dword %0, %[q0], off\n\t"
      "global_load_dword %1, %[q1], off\n\t"
      "global_load_dword %2, %[q2], off\n\t"
      "global_load_dword %3, %[q3], off\n\t"
      "s_waitcnt vmcnt(0)"
      : "=&v"(u0), "=&v"(u1), "=&v"(u2), "=&v"(u3)
      : [q0] "v"(p0), [q1] "v"(p1), [q2] "v"(p2), [q3] "v"(p3));
}

// ---------------- GRU weight evolution (both layers, single-bf16 RNE) + zero counts ----
__global__ void gru_evolve2_k(const float* __restrict__ W01, const float* __restrict__ wih1,
                              const float* __restrict__ whh1, const float* __restrict__ bih1,
                              const float* __restrict__ bhh1,
                              const float* __restrict__ W02, const float* __restrict__ wih2,
                              const float* __restrict__ whh2, const float* __restrict__ bih2,
                              const float* __restrict__ bhh2,
                              unsigned short* __restrict__ Bhi1, unsigned short* __restrict__ Bhi2,
                              int* __restrict__ counts, int n) {
  if ((int)blockIdx.x >= 128) {
    int i = ((int)blockIdx.x - 128) * SB + threadIdx.x;
    if (i < n) counts[i] = 0;
    return;
  }
  int t = blockIdx.x * 256 + threadIdx.x;     // 0..32767
  int layer = t >> 14;
  int tt = t & 16383;
  const float* W0  = layer ? W02  : W01;
  const float* wih = layer ? wih2 : wih1;
  const float* whh = layer ? whh2 : whh1;
  const float* bih = layer ? bih2 : bih1;
  const float* bhh = layer ? bhh2 : bhh1;
  unsigned short* Bhi = layer ? Bhi2 : Bhi1;
  int i = tt >> 7, j = tt & 127;      // i = k (feature) index, j = w_col index
  const float4* w0r = (const float4*)(W0 + (size_t)i * F);
  float gi[3], gh[3];
#pragma unroll
  for (int g = 0; g < 3; ++g) {
    const float4* wr = (const float4*)(wih + (size_t)(g * F + j) * F);
    const float4* hr = (const float4*)(whh + (size_t)(g * F + j) * F);
    float si = 0.f, sh = 0.f;
    for (int k = 0; k < F / 4; ++k) {
      float4 a = w0r[k];
      float4 b = wr[k];
      float4 c = hr[k];
      si += a.x * b.x + a.y * b.y + a.z * b.z + a.w * b.w;
      sh += a.x * c.x + a.y * c.y + a.z * c.z + a.w * c.w;
    }
    gi[g] = si + bih[g * F + j];
    gh[g] = sh + bhh[g * F + j];
  }
  float r = 1.0f / (1.0f + expf(-(gi[0] + gh[0])));
  float z = 1.0f / (1.0f + expf(-(gi[1] + gh[1])));
  float nn = tanhf(gi[2] + r * gh[2]);
  float val = (1.0f - z) * nn + z * W0[(size_t)i * F + j];

  int kstep = i >> 5, kl = i & 31;
  int lane = (kl >> 3) * 16 + (j & 15);
  int tile = j >> 4;
  int idx = ((kstep * 8 + tile) * 64 + lane) * 8 + (kl & 7);
  Bhi[idx] = bf16_rne(val);
}

// ---------------- CSR build ----------------
__global__ void count_rank_k(const int* __restrict__ dst, int* __restrict__ counts,
                             int* __restrict__ rank, int E) {
  int e = blockIdx.x * blockDim.x + threadIdx.x;
  if (e < E) rank[e] = atomicAdd(&counts[dst[e]], 1);
}

__global__ void scan_local_k(const int* __restrict__ counts, int* __restrict__ incl,
                             int* __restrict__ blocksum, int n) {
  __shared__ int sh[SB];
  int gid = blockIdx.x * SB + threadIdx.x;
  int v = (gid < n) ? counts[gid] : 0;
  sh[threadIdx.x] = v;
  __syncthreads();
  for (int off = 1; off < SB; off <<= 1) {
    int t = 0;
    if ((int)threadIdx.x >= off) t = sh[threadIdx.x - off];
    __syncthreads();
    if ((int)threadIdx.x >= off) sh[threadIdx.x] += t;
    __syncthreads();
  }
  if (gid < n) incl[gid] = sh[threadIdx.x];
  if (threadIdx.x == SB - 1) blocksum[blockIdx.x] = sh[SB - 1];
}

__global__ void scan_finish_k(const int* __restrict__ counts, const int* __restrict__ incl,
                              const int* __restrict__ blocksum, int* __restrict__ rowptr,
                              float* __restrict__ dinv, int n, int nb) {
  __shared__ int sh[SB];
  __shared__ int orig[SB];
  int v = ((int)threadIdx.x < nb) ? blocksum[threadIdx.x] : 0;
  sh[threadIdx.x] = v;
  orig[threadIdx.x] = v;
  __syncthreads();
  for (int off = 1; off < SB; off <<= 1) {
    int t = 0;
    if ((int)threadIdx.x >= off) t = sh[threadIdx.x - off];
    __syncthreads();
    if ((int)threadIdx.x >= off) sh[threadIdx.x] += t;
    __syncthreads();
  }
  int myoff = sh[blockIdx.x] - orig[blockIdx.x];
  int gid = blockIdx.x * SB + threadIdx.x;
  if (gid >= n) return;
  int c = counts[gid];
  int inc = myoff + incl[gid];
  rowptr[gid] = inc - c;
  dinv[gid] = rsqrtf((float)c + 1.0f);
  if (gid == n - 1) rowptr[n] = inc;
}

// fill stores PRE-SHIFTED src (src<<7 = byte offset of the 128B fp8 row).
__device__ __forceinline__ void fill_body(int bid, const int* __restrict__ src,
                                          const int* __restrict__ dst,
                                          const int* __restrict__ rank,
                                          const int* __restrict__ rowptr,
                                          int* __restrict__ csr_src, int E) {
  int e = bid * 256 + (int)threadIdx.x;
  if (e < E) {
    int d = dst[e];
    csr_src[rowptr[d] + rank[e]] = src[e] << 7;
  }
}

// ---------------- MFMA GEMM: fp8 rows (128 B), single-bf16 inputs --------------------
__device__ __forceinline__ void gemm_body(int bid, const float* __restrict__ X,
                                          const unsigned short* __restrict__ Bhi,
                                          const float* __restrict__ dinv,
                                          unsigned* __restrict__ Y, int nrows) {
  int wid = bid * 4 + ((int)threadIdx.x >> 6);
  int lane = threadIdx.x & 63;
  int ng = (nrows + 15) >> 4;
  if (wid >= ng) return;
  int g = __builtin_amdgcn_readfirstlane(wid);
  int q = lane >> 4, m = lane & 15;
  int rowA = g * 16 + m;
  if (rowA >= nrows) rowA = nrows - 1;

  f32x4 acc[8];
#pragma unroll
  for (int t = 0; t < 8; ++t) { acc[t].x = 0.f; acc[t].y = 0.f; acc[t].z = 0.f; acc[t].w = 0.f; }

#pragma unroll
  for (int s = 0; s < 4; ++s) {
    const float* xp = X + (size_t)rowA * F + s * 32 + q * 8;
    float4 xa = *(const float4*)xp;
    float4 xb = *(const float4*)(xp + 4);
    float xv[8] = {xa.x, xa.y, xa.z, xa.w, xb.x, xb.y, xb.z, xb.w};
    bf16x8 xh;
#pragma unroll
    for (int j = 0; j < 8; ++j) xh[j] = (short)bf16_rne(xv[j]);
#pragma unroll
    for (int t = 0; t < 8; ++t) {
      size_t boff = ((size_t)(s * 8 + t) * 64 + lane) * 8;
      bf16x8 wh = *(const bf16x8*)(Bhi + boff);
      acc[t] = __builtin_amdgcn_mfma_f32_16x16x32_bf16(wh, xh, acc[t], 0, 0, 0);
    }
  }

  int row = g * 16 + m;
  if (row < nrows) {
    float dd = dinv[row];
    unsigned* yr = Y + (size_t)row * 32 + q;   // lane q owns dword t*4+q
#pragma unroll
    for (int t = 0; t < 8; ++t) {
      int p = __builtin_amdgcn_cvt_pk_fp8_f32(dd * acc[t].x, dd * acc[t].y, 0, false);
      p = __builtin_amdgcn_cvt_pk_fp8_f32(dd * acc[t].z, dd * acc[t].w, p, true);
      yr[t * 4] = (unsigned)p;
    }
  }
}

__global__ void gemm_mfma_k(const float* __restrict__ X, const unsigned short* __restrict__ Bhi,
                            const float* __restrict__ dinv, unsigned* __restrict__ Y,
                            int nrows) {
  gemm_body(blockIdx.x, X, Bhi, dinv, Y, nrows);
}

// fused: blocks [0, ngemm) do layer-1 gemm; [ngemm, ...) do csr fill.
__global__ void fill_gemm_k(const float* __restrict__ X, const unsigned short* __restrict__ Bhi,
                            const float* __restrict__ dinv, unsigned* __restrict__ Y,
                            int nrows, int ngemm,
                            const int* __restrict__ src, const int* __restrict__ dst,
                            const int* __restrict__ rank, const int* __restrict__ rowptr,
                            int* __restrict__ csr_src, int E) {
  if ((int)blockIdx.x < ngemm)
    gemm_body(blockIdx.x, X, Bhi, dinv, Y, nrows);
  else
    fill_body((int)blockIdx.x - ngemm, src, dst, rank, rowptr, csr_src, E);
}

// ---------------- gather aggregation: fp8 rows (128 B), asm-forced 8-deep MLP -------
// R2 structure (best: 44.4us) with the ONLY change being asm-forced gather groups.
// One wave per node. Lanes 0-31 even edges, 32-63 odd edges; lane (half,hm) loads one
// dword = 4 fp8 cols. Per-lane csr base (cp = csr_src + half) -> no select chains.
// R0-R4 lesson: every C-level variant compiled to VGPR 28-32 = ~4 outstanding vmem.
// gather8() guarantees 8 in flight per wave. This is the falsification experiment for
// the compiler-serialization theory: VGPR must rise to ~48+; if time doesn't move,
// the ~2.4 TB/s random-row-gather rate is a memory-system floor.
template <bool FUSE_LOGITS>
__global__ void agg_fp8_k(const int* __restrict__ rowptr, const int* __restrict__ csr_src,
                          const float* __restrict__ dinv, const unsigned* __restrict__ xwp,
                          float* __restrict__ hout,
                          const float* __restrict__ lw, const float* __restrict__ lb,
                          float* __restrict__ outp, int n) {
  int wave = (int)((blockIdx.x * blockDim.x + threadIdx.x) >> 6);
  int lane = threadIdx.x & 63;
  if (wave >= n) return;
  int node = __builtin_amdgcn_readfirstlane(wave);
  int half = lane >> 5, hm = lane & 31;
  float dd = dinv[node];
  const char* __restrict__ cb = (const char*)xwp;   // row = 128 bytes
  unsigned loff = (unsigned)(hm << 2);
  f32x2 acc0 = {0.f, 0.f}, acc1 = {0.f, 0.f};
  f32x2 bcc0 = {0.f, 0.f}, bcc1 = {0.f, 0.f};

#define DEC(U, A, B)                                           \
  do {                                                         \
    (A) += __builtin_amdgcn_cvt_pk_f32_fp8((int)(U), false);   \
    (B) += __builtin_amdgcn_cvt_pk_f32_fp8((int)(U), true);    \
  } while (0)

  // self-loop (lower half only; upper half contributes 0)
  {
    unsigned u = *(const unsigned*)(cb + ((((unsigned)node) << 7) | loff));
    if (half) u = 0u;
    DEC(u, acc0, acc1);
  }

  int b = rowptr[node], e = rowptr[node + 1];
  const int* __restrict__ cp = csr_src + half;   // per-lane: cp[i+2k] = edge i+2k+half
  int i = b;
  // 16-edge main loop: 8 csr loads (C) feed ONE asm block of 8 gathers (all in flight)
  for (; i + 16 <= e; i += 16) {
    int s0 = cp[i + 0],  s1 = cp[i + 2],  s2 = cp[i + 4],  s3 = cp[i + 6];
    int s4 = cp[i + 8],  s5 = cp[i + 10], s6 = cp[i + 12], s7 = cp[i + 14];
    unsigned u0, u1, u2, u3, u4, u5, u6, u7;
    gather8(cb + (((unsigned)s0) | loff), cb + (((unsigned)s1) | loff),
            cb + (((unsigned)s2) | loff), cb + (((unsigned)s3) | loff),
            cb + (((unsigned)s4) | loff), cb + (((unsigned)s5) | loff),
            cb + (((unsigned)s6) | loff), cb + (((unsigned)s7) | loff),
            u0, u1, u2, u3, u4, u5, u6, u7);
    DEC(u0, acc0, acc1);
    DEC(u1, bcc0, bcc1);
    DEC(u2, acc0, acc1);
    DEC(u3, bcc0, bcc1);
    DEC(u4, acc0, acc1);
    DEC(u5, bcc0, bcc1);
    DEC(u6, acc0, acc1);
    DEC(u7, bcc0, bcc1);
  }
  // 8-edge tail (asm-forced 4 gathers)
  if (i + 8 <= e) {
    int s0 = cp[i + 0], s1 = cp[i + 2], s2 = cp[i + 4], s3 = cp[i + 6];
    unsigned u0, u1, u2, u3;
    gather4(cb + (((unsigned)s0) | loff), cb + (((unsigned)s1) | loff),
            cb + (((unsigned)s2) | loff), cb + (((unsigned)s3) | loff),
            u0, u1, u2, u3);
    DEC(u0, acc0, acc1);
    DEC(u1, bcc0, bcc1);
    DEC(u2, acc0, acc1);
    DEC(u3, bcc0, bcc1);
    i += 8;
  }
  // 4-edge tail
  if (i + 4 <= e) {
    int s0 = cp[i + 0], s1 = cp[i + 2];
    unsigned u0 = *(const unsigned*)(cb + (((unsigned)s0) | loff));
    unsigned u1 = *(const unsigned*)(cb + (((unsigned)s1) | loff));
    DEC(u0, acc0, acc1);
    DEC(u1, bcc0, bcc1);
    i += 4;
  }
  // 2-edge tail
  if (i + 2 <= e) {
    int s0 = cp[i];
    unsigned u = *(const unsigned*)(cb + (((unsigned)s0) | loff));
    DEC(u, acc0, acc1);
    i += 2;
  }
  // single remaining edge: half 0 processes it; half 1 clamps the csr index
  if (i < e) {
    int idx = i + half;
    if (idx >= e) idx = e - 1;
    int s = csr_src[idx];
    unsigned u = *(const unsigned*)(cb + (((unsigned)s) | loff));
    if (half) u = 0u;
    DEC(u, bcc0, bcc1);
  }
#undef DEC
  acc0 += bcc0;
  acc1 += bcc1;

  // combine the two halves (both end up with the full sum)
  acc0.x += __shfl_xor(acc0.x, 32);
  acc0.y += __shfl_xor(acc0.y, 32);
  acc1.x += __shfl_xor(acc1.x, 32);
  acc1.y += __shfl_xor(acc1.y, 32);

  float h0 = fmaxf(dd * acc0.x, 0.f);
  float h1 = fmaxf(dd * acc0.y, 0.f);
  float h2 = fmaxf(dd * acc1.x, 0.f);
  float h3 = fmaxf(dd * acc1.y, 0.f);

  if (!FUSE_LOGITS) {
    if (half == 0) {
      *(float4*)(hout + (size_t)node * F + hm * 4) = make_float4(h0, h1, h2, h3);
    }
  } else {
    float acc[C_OUT];
#pragma unroll
    for (int c = 0; c < C_OUT; ++c) {
      float4 w = *(const float4*)(lw + (size_t)c * F + hm * 4);
      float v = h0 * w.x + h1 * w.y + h2 * w.z + h3 * w.w;
      v += __shfl_xor(v, 1); v += __shfl_xor(v, 2);
      v += __shfl_xor(v, 4); v += __shfl_xor(v, 8);
      v += __shfl_xor(v, 16);
      acc[c] = v + lb[c];
    }
    float mx = acc[0];
#pragma unroll
    for (int c = 1; c < C_OUT; ++c) mx = fmaxf(mx, acc[c]);
    float s = 0.f;
#pragma unroll
    for (int c = 0; c < C_OUT; ++c) s += expf(acc[c] - mx);
    float lse = mx + logf(s);
#pragma unroll
    for (int c = 0; c < C_OUT; ++c)
      if (lane == c) outp[(size_t)node * C_OUT + c] = acc[c] - lse;
  }
}

extern "C" void kernel_launch(void* const* d_in, const int* in_sizes, int n_in,
                              void* d_out, int out_size, void* d_ws, size_t ws_size,
                              hipStream_t stream) {
  const float* x    = (const float*)d_in[0];
  const int*   ei   = (const int*)d_in[1];
  const float* W1   = (const float*)d_in[2];
  const float* wih1 = (const float*)d_in[3];
  const float* whh1 = (const float*)d_in[4];
  const float* bih1 = (const float*)d_in[5];
  const float* bhh1 = (const float*)d_in[6];
  const float* W2   = (const float*)d_in[7];
  const float* wih2 = (const float*)d_in[8];
  const float* whh2 = (const float*)d_in[9];
  const float* bih2 = (const float*)d_in[10];
  const float* bhh2 = (const float*)d_in[11];
  const float* lw   = (const float*)d_in[12];
  const float* lb   = (const float*)d_in[13];
  float* out = (float*)d_out;

  int N = in_sizes[0] / F;
  int E = in_sizes[1] / 2;
  const int* src = ei;
  const int* dst = ei + E;
  int nb = (N + SB - 1) / SB;   // 196 (must be <= 256)
  int ng = (N + 15) / 16;
  int ngemm = (ng + 3) / 4;
  int nfill = (E + 255) / 256;
  int nagg = (N + 3) / 4;

  float* ws = (float*)d_ws;
  unsigned* bufA = (unsigned*)ws;                // N*32 dwords (fp8 rows, 128 B)
  float* bufB = (float*)(bufA + (size_t)N * 32); // N*F floats (h)
  float* dinv = bufB + (size_t)N * F;            // N
  unsigned short* Bhi1 = (unsigned short*)(dinv + N);  // 16384
  unsigned short* Bhi2 = Bhi1 + F * F;                 // 16384
  int* counts = (int*)(Bhi2 + F * F);            // N
  int* rowptr = counts + N;                      // N+1
  int* rank   = rowptr + N + 1;                  // E
  int* incl   = rank + E;                        // N
  int* blocksum = incl + N;                      // 256
  int* csr_src = blocksum + 256;                 // E

  gru_evolve2_k<<<128 + nb, 256, 0, stream>>>(W1, wih1, whh1, bih1, bhh1,
                                              W2, wih2, whh2, bih2, bhh2,
                                              Bhi1, Bhi2, counts, N);

  count_rank_k<<<(E + 255) / 256, 256, 0, stream>>>(dst, counts, rank, E);
  scan_local_k<<<nb, SB, 0, stream>>>(counts, incl, blocksum, N);
  scan_finish_k<<<nb, SB, 0, stream>>>(counts, incl, blocksum, rowptr, dinv, N, nb);

  // layer 1 gemm + csr fill (independent; fused dispatch)
  fill_gemm_k<<<ngemm + nfill, 256, 0, stream>>>(x, Bhi1, dinv, bufA, N, ngemm,
                                                 src, dst, rank, rowptr, csr_src, E);
  agg_fp8_k<false><<<nagg, 256, 0, stream>>>(rowptr, csr_src, dinv, bufA, bufB,
                                             nullptr, nullptr, nullptr, N);

  // layer 2 (logits fused)
  gemm_mfma_k<<<ngemm, 256, 0, stream>>>(bufB, Bhi2, dinv, bufA, N);
  agg_fp8_k<true><<<nagg, 256, 0, stream>>>(rowptr, csr_src, dinv, bufA, nullptr,
                                            lw, lb, out, N);
}